// Round 5
// baseline (449.507 us; speedup 1.0000x reference)
//
#include <hip/hip_runtime.h>
#include <stdint.h>

typedef unsigned short ushort_t;
typedef __attribute__((ext_vector_type(8))) short bf16x8;   // 8 bf16 in 4 VGPRs
typedef __attribute__((ext_vector_type(4))) float f32x4;

// ---------- helpers ----------
__device__ __forceinline__ unsigned short f2b(float f) {
  unsigned u = __float_as_uint(f);
  u += 0x7fffu + ((u >> 16) & 1u);   // round-to-nearest-even
  return (unsigned short)(u >> 16);
}

__device__ __forceinline__ void async16(const void* g, void* l) {
  __builtin_amdgcn_global_load_lds(
      (const __attribute__((address_space(1))) void*)g,
      (__attribute__((address_space(3))) void*)l, 16, 0, 0);
}

// ---------- LayerNorm (fp32 in -> bf16 out), one block per row, C=1024 ----------
__global__ __launch_bounds__(256) void ln_kernel(
    const float* __restrict__ x, const float* __restrict__ g,
    const float* __restrict__ be, ushort_t* __restrict__ out) {
  const int C = 1024;
  int row = blockIdx.x;
  const float4* xr = (const float4*)(x + (size_t)row * C);
  int tid = threadIdx.x;
  float4 v = xr[tid];
  float s = v.x + v.y + v.z + v.w;
  float sq = v.x * v.x + v.y * v.y + v.z * v.z + v.w * v.w;
  #pragma unroll
  for (int off = 32; off > 0; off >>= 1) {
    s += __shfl_xor(s, off);
    sq += __shfl_xor(sq, off);
  }
  __shared__ float ss[4], ssq[4];
  int wv = tid >> 6;
  if ((tid & 63) == 0) { ss[wv] = s; ssq[wv] = sq; }
  __syncthreads();
  s = ss[0] + ss[1] + ss[2] + ss[3];
  sq = ssq[0] + ssq[1] + ssq[2] + ssq[3];
  float mu = s * (1.f / C);
  float var = sq * (1.f / C) - mu * mu;
  float rs = rsqrtf(var + 1e-5f);
  float4 gv = ((const float4*)g)[tid];
  float4 bv = ((const float4*)be)[tid];
  ushort4 o;
  o.x = f2b((v.x - mu) * rs * gv.x + bv.x);
  o.y = f2b((v.y - mu) * rs * gv.y + bv.y);
  o.z = f2b((v.z - mu) * rs * gv.z + bv.z);
  o.w = f2b((v.w - mu) * rs * gv.w + bv.w);
  ((ushort4*)(out + (size_t)row * C))[tid] = o;
}

// ---------- batched transpose + fp32->bf16 cast: in (bz,R,Cin) -> out (bz,Cin,R) ----------
__global__ __launch_bounds__(256) void transpose_cast_kernel(
    const float* __restrict__ in, ushort_t* __restrict__ out, int R, int Cin) {
  __shared__ float tile[32][33];
  int bz = blockIdx.z;
  in += (size_t)bz * R * Cin;
  out += (size_t)bz * R * Cin;
  int c0 = blockIdx.x * 32, r0 = blockIdx.y * 32;
  int tx = threadIdx.x, ty = threadIdx.y;
  #pragma unroll
  for (int i = 0; i < 4; i++)
    tile[ty + 8 * i][tx] = in[(size_t)(r0 + ty + 8 * i) * Cin + c0 + tx];
  __syncthreads();
  #pragma unroll
  for (int i = 0; i < 4; i++)
    out[(size_t)(c0 + ty + 8 * i) * R + r0 + tx] = f2b(tile[tx][ty + 8 * i]);
}

// ---------- V transpose: QKV (4096,3072) bf16 -> Vt (B*H, 64, 2048) bf16 ----------
__global__ __launch_bounds__(256) void transpose_v_kernel(
    const ushort_t* __restrict__ qkv, ushort_t* __restrict__ vt) {
  __shared__ ushort_t tile[32][33];
  int bh = blockIdx.z;
  int b = bh >> 4, h = bh & 15;
  int d0 = blockIdx.x * 32, t0 = blockIdx.y * 32;
  int tx = threadIdx.x, ty = threadIdx.y;
  #pragma unroll
  for (int i = 0; i < 4; i++)
    tile[ty + 8 * i][tx] =
        qkv[(size_t)(b * 2048 + t0 + ty + 8 * i) * 3072 + 2048 + h * 64 + d0 + tx];
  __syncthreads();
  #pragma unroll
  for (int i = 0; i < 4; i++)
    vt[(size_t)(bh * 64 + d0 + ty + 8 * i) * 2048 + t0 + tx] = tile[tx][ty + 8 * i];
}

// ---------- GEMM: out(M,N) = A(M,K) @ Bt(N,K)^T, bf16 in ----------
// FLAGS: 1 = relu, 2 = bf16 output (else fp32), 4 = add bias, 8 = add resid.
template <int N, int K, int FLAGS>
__global__ __launch_bounds__(256, 2) void gemm_bt_kernel(
    const ushort_t* __restrict__ A, const ushort_t* __restrict__ Bt,
    const float* __restrict__ bias, const float* __restrict__ resid,
    void* __restrict__ outv) {
  __shared__ ushort_t Als[128 * 32];
  __shared__ ushort_t Bls[128 * 32];
  int tid = threadIdx.x, w = tid >> 6, lane = tid & 63, quad = lane >> 4, l16 = lane & 15;
  int bn0 = blockIdx.x * 128, bm0 = blockIdx.y * 128;
  int wm = (w >> 1) * 64, wn = (w & 1) * 64;
  f32x4 acc[4][4];
  #pragma unroll
  for (int i = 0; i < 4; i++)
    #pragma unroll
    for (int j = 0; j < 4; j++) acc[i][j] = f32x4{0.f, 0.f, 0.f, 0.f};
  const ushort_t* Ag = A + (size_t)bm0 * K;
  const ushort_t* Bg = Bt + (size_t)bn0 * K;
  int c0 = w * 128 + lane;
  int r0s = c0 >> 2, co0 = (c0 & 3) * 8;
  int c1 = c0 + 64;
  int r1s = c1 >> 2, co1 = (c1 & 3) * 8;
  for (int k0 = 0; k0 < K; k0 += 32) {
    async16(Ag + (size_t)r0s * K + k0 + co0, &Als[w * 1024]);
    async16(Bg + (size_t)r0s * K + k0 + co0, &Bls[w * 1024]);
    async16(Ag + (size_t)r1s * K + k0 + co1, &Als[w * 1024 + 512]);
    async16(Bg + (size_t)r1s * K + k0 + co1, &Bls[w * 1024 + 512]);
    __syncthreads();
    bf16x8 af[4], bf[4];
    #pragma unroll
    for (int i = 0; i < 4; i++)
      af[i] = *(const bf16x8*)&Als[(wm + i * 16 + l16) * 32 + quad * 8];
    #pragma unroll
    for (int j = 0; j < 4; j++)
      bf[j] = *(const bf16x8*)&Bls[(wn + j * 16 + l16) * 32 + quad * 8];
    #pragma unroll
    for (int i = 0; i < 4; i++)
      #pragma unroll
      for (int j = 0; j < 4; j++)
        acc[i][j] = __builtin_amdgcn_mfma_f32_16x16x32_bf16(af[i], bf[j], acc[i][j], 0, 0, 0);
    __syncthreads();
  }
  #pragma unroll
  for (int i = 0; i < 4; i++)
    #pragma unroll
    for (int j = 0; j < 4; j++)
      #pragma unroll
      for (int r = 0; r < 4; r++) {
        int row = bm0 + wm + i * 16 + quad * 4 + r;
        int col = bn0 + wn + j * 16 + l16;
        float v = acc[i][j][r];
        if constexpr (FLAGS & 4) v += bias[col];
        if constexpr (FLAGS & 8) v += resid[(size_t)row * N + col];
        if constexpr (FLAGS & 1) v = fmaxf(v, 0.f);
        if constexpr ((FLAGS & 2) != 0)
          ((ushort_t*)outv)[(size_t)row * N + col] = f2b(v);
        else
          ((float*)outv)[(size_t)row * N + col] = v;
      }
}

// ---------- causal flash attention, S^T formulation, key-split across waves ----------
// S^T = K·Q^T (operand-swapped MFMA): each lane holds scores for ONE q-row
// (q = q0 + l16), keys in-lane -> softmax max/sum are in-lane trees + 2
// shuffles; m/l/alpha are per-lane scalars. P^T B-fragments for O^T += V^T·P^T
// built via 16 ds_bpermute + selects (no LDS round-trip). Merge of 4 key-split
// waves via LDS at the end (2 barriers total per block).
__global__ __launch_bounds__(256, 2) void attn_kernel(
    const ushort_t* __restrict__ qkv, const ushort_t* __restrict__ vt,
    ushort_t* __restrict__ out) {
  const int T = 2048, CC = 3072;
  __shared__ float Mls[4][16], Lls[4][16];
  __shared__ float Ols[4][64][17];   // stride 17 floats: conflict-free b32
  int fid = blockIdx.y * 32 + blockIdx.x;          // grid (32,128)
  int bh = (fid & 7) * 4 + ((fid >> 3) & 3);       // 4 heads per XCD slot
  int qt = 127 - (fid >> 5);                       // longest q-tiles first
  int b = bh >> 4, h = bh & 15;
  int q0 = qt * 16;
  int tid = threadIdx.x, w = tid >> 6, lane = tid & 63, quad = lane >> 4, l16 = lane & 15;
  // Q fragments used as B-operand: n=l16 -> q-row q0+l16, k=quad*8+j -> d
  const ushort_t* qp = qkv + (size_t)(b * T + q0 + l16) * CC + h * 64 + quad * 8;
  bf16x8 aq[2] = { *(const bf16x8*)qp, *(const bf16x8*)(qp + 32) };
  const ushort_t* kbase = qkv + (size_t)(b * T + l16) * CC + 1024 + h * 64 + quad * 8;
  const ushort_t* vbase = vt + (size_t)(bh * 64 + l16) * T + quad * 8;
  f32x4 O[4];   // O^T: per lane q=l16, d = dt*16 + quad*4 + reg
  #pragma unroll
  for (int i = 0; i < 4; i++) O[i] = f32x4{0.f, 0.f, 0.f, 0.f};
  float mrun = -1e30f, lrun = 0.f;   // per-lane scalars (q = l16)
  int kbd = q0 >> 6;                 // diagonal key block
  int trow = q0 + l16;
  bf16x8 kf[4][2];
  if (w <= kbd) {
    #pragma unroll
    for (int tn = 0; tn < 4; tn++)
      #pragma unroll
      for (int ks = 0; ks < 2; ks++)
        kf[tn][ks] = *(const bf16x8*)(kbase + (size_t)(w * 64 + tn * 16) * CC + ks * 32);
  }
  int src0 = (quad & 1) * 32 + l16;   // bpermute source lanes for P^T B-frag
  int src1 = src0 + 16;
  bool hiq = quad >= 2;
  for (int kb = w; kb <= kbd; kb += 4) {
    int s0 = kb * 64;
    // V^T fragments (A-operand): m=l16 -> d-row, k=quad*8+j -> key; issued early
    bf16x8 vf[4][2];
    #pragma unroll
    for (int dt = 0; dt < 4; dt++)
      #pragma unroll
      for (int ks = 0; ks < 2; ks++)
        vf[dt][ks] = *(const bf16x8*)(vbase + (size_t)(dt * 16) * T + s0 + ks * 32);
    // S^T = K Q^T : st[t][r] = S[key=s0+t*16+quad*4+r][q0+l16]
    f32x4 st[4];
    #pragma unroll
    for (int t = 0; t < 4; t++) {
      st[t] = f32x4{0.f, 0.f, 0.f, 0.f};
      #pragma unroll
      for (int ks = 0; ks < 2; ks++)
        st[t] = __builtin_amdgcn_mfma_f32_16x16x32_bf16(kf[t][ks], aq[ks], st[t], 0, 0, 0);
    }
    // prefetch next kf while softmax runs
    bf16x8 kfn[4][2];
    int kbn = kb + 4;
    if (kbn <= kbd) {
      #pragma unroll
      for (int tn = 0; tn < 4; tn++)
        #pragma unroll
        for (int ks = 0; ks < 2; ks++)
          kfn[tn][ks] = *(const bf16x8*)(kbase + (size_t)(kbn * 64 + tn * 16) * CC + ks * 32);
    }
    bool diag = (kb == kbd);
    // mask + in-lane max over 16 keys + 2 cross-quad shuffles
    float sv[4][4];
    float vmax = -1e30f;
    #pragma unroll
    for (int t = 0; t < 4; t++)
      #pragma unroll
      for (int r = 0; r < 4; r++) {
        float sc = st[t][r] * 0.03125f;   // * C^-0.5 (faithful: 1/32)
        int scol = s0 + t * 16 + quad * 4 + r;
        if (diag && scol > trow) sc = -1e30f;
        sv[t][r] = sc;
        vmax = fmaxf(vmax, sc);
      }
    vmax = fmaxf(vmax, __shfl_xor(vmax, 16));
    vmax = fmaxf(vmax, __shfl_xor(vmax, 32));
    float mnew = fmaxf(mrun, vmax);
    float alpha = __expf(mrun - mnew);
    mrun = mnew;
    // exp + in-lane sum + pack to bf16 pairs
    float psum = 0.f;
    int pk[4][2];
    #pragma unroll
    for (int t = 0; t < 4; t++) {
      float p0 = __expf(sv[t][0] - mnew);
      float p1 = __expf(sv[t][1] - mnew);
      float p2 = __expf(sv[t][2] - mnew);
      float p3 = __expf(sv[t][3] - mnew);
      psum += (p0 + p1) + (p2 + p3);
      pk[t][0] = (int)((unsigned)f2b(p0) | ((unsigned)f2b(p1) << 16));
      pk[t][1] = (int)((unsigned)f2b(p2) | ((unsigned)f2b(p3) << 16));
    }
    psum += __shfl_xor(psum, 16);
    psum += __shfl_xor(psum, 32);
    lrun = lrun * alpha + psum;
    #pragma unroll
    for (int dt = 0; dt < 4; dt++) O[dt] *= alpha;
    // O^T += V^T P^T ; P^T B-frag: n=l16=q, k=quad*8+j=key, via bpermute
    #pragma unroll
    for (int g32 = 0; g32 < 2; g32++) {
      int t0 = 2 * g32, t1 = t0 + 1;
      int a0 = __shfl(pk[t0][0], src0), b0 = __shfl(pk[t1][0], src0);
      int a1 = __shfl(pk[t0][1], src0), b1 = __shfl(pk[t1][1], src0);
      int a2 = __shfl(pk[t0][0], src1), b2 = __shfl(pk[t1][0], src1);
      int a3 = __shfl(pk[t0][1], src1), b3 = __shfl(pk[t1][1], src1);
      union { int4 i; bf16x8 h; } u;
      u.i.x = hiq ? b0 : a0;
      u.i.y = hiq ? b1 : a1;
      u.i.z = hiq ? b2 : a2;
      u.i.w = hiq ? b3 : a3;
      #pragma unroll
      for (int dt = 0; dt < 4; dt++)
        O[dt] = __builtin_amdgcn_mfma_f32_16x16x32_bf16(vf[dt][g32], u.h, O[dt], 0, 0, 0);
    }
    #pragma unroll
    for (int tn = 0; tn < 4; tn++)
      #pragma unroll
      for (int ks = 0; ks < 2; ks++)
        kf[tn][ks] = kfn[tn][ks];
  }
  // ---- merge the 4 waves' partial states ----
  if (quad == 0) { Mls[w][l16] = mrun; Lls[w][l16] = lrun; }
  __syncthreads();
  float m0 = Mls[0][l16], m1 = Mls[1][l16], m2 = Mls[2][l16], m3 = Mls[3][l16];
  float mt = fmaxf(fmaxf(m0, m1), fmaxf(m2, m3));
  float lt = Lls[0][l16] * __expf(m0 - mt) + Lls[1][l16] * __expf(m1 - mt) +
             Lls[2][l16] * __expf(m2 - mt) + Lls[3][l16] * __expf(m3 - mt);
  float myfw = __expf(mrun - mt);
  #pragma unroll
  for (int dt = 0; dt < 4; dt++)
    #pragma unroll
    for (int r = 0; r < 4; r++)
      Ols[w][lane][dt * 4 + r] = O[dt][r] * myfw;
  __syncthreads();
  float inv = 1.f / lt;
  #pragma unroll
  for (int dt = 0; dt < 4; dt++) {
    ushort4 o;
    unsigned short* op = (unsigned short*)&o;
    #pragma unroll
    for (int r = 0; r < 4; r++) {
      float s = Ols[0][lane][dt * 4 + r] + Ols[1][lane][dt * 4 + r] +
                Ols[2][lane][dt * 4 + r] + Ols[3][lane][dt * 4 + r];
      op[r] = f2b(s * inv);
    }
    *(ushort4*)&out[(size_t)(b * T + trow) * 1024 + h * 64 + dt * 16 + quad * 4] = o;
  }
}

// ---------- host ----------
extern "C" void kernel_launch(void* const* d_in, const int* in_sizes, int n_in,
                              void* d_out, int out_size, void* d_ws, size_t ws_size,
                              hipStream_t stream) {
  const int B = 2, T = 2048, C = 1024, H = 16, D = 64, FF = 4096;
  const int M = B * T;  // 4096
  const float* x   = (const float*)d_in[0];
  const float* Wq  = (const float*)d_in[1];
  const float* Wk  = (const float*)d_in[2];
  const float* Wv  = (const float*)d_in[3];
  const float* Wo  = (const float*)d_in[4];
  const float* bo  = (const float*)d_in[5];
  const float* W1  = (const float*)d_in[6];
  const float* b1  = (const float*)d_in[7];
  const float* W2  = (const float*)d_in[8];
  const float* b2  = (const float*)d_in[9];
  const float* g1  = (const float*)d_in[10];
  const float* be1 = (const float*)d_in[11];
  const float* g2  = (const float*)d_in[12];
  const float* be2 = (const float*)d_in[13];
  float* out = (float*)d_out;

  char* ws = (char*)d_ws;
  size_t off = 0;
  auto alloc = [&](size_t bytes) {
    void* p = ws + off;
    off += (bytes + 255) & ~(size_t)255;
    return p;
  };
  ushort_t* qkvt = (ushort_t*)alloc((size_t)3 * C * C * 2);
  ushort_t* wot  = (ushort_t*)alloc((size_t)C * C * 2);
  ushort_t* w1t  = (ushort_t*)alloc((size_t)FF * C * 2);
  ushort_t* w2t  = (ushort_t*)alloc((size_t)C * FF * 2);
  ushort_t* hbuf = (ushort_t*)alloc((size_t)M * C * 2);
  ushort_t* big  = (ushort_t*)alloc((size_t)M * FF * 2);
  ushort_t* vtb  = (ushort_t*)alloc((size_t)M * C * 2);
  ushort_t* aout = (ushort_t*)alloc((size_t)M * C * 2);
  float*    x2   = (float*)alloc((size_t)M * C * 4);

  dim3 tb(32, 8);
  transpose_cast_kernel<<<dim3(D / 32, C / 32, H), tb, 0, stream>>>(Wq, qkvt, C, D);
  transpose_cast_kernel<<<dim3(D / 32, C / 32, H), tb, 0, stream>>>(Wk, qkvt + (size_t)C * C, C, D);
  transpose_cast_kernel<<<dim3(D / 32, C / 32, H), tb, 0, stream>>>(Wv, qkvt + (size_t)2 * C * C, C, D);
  transpose_cast_kernel<<<dim3(C / 32, C / 32, 1), tb, 0, stream>>>(Wo, wot, C, C);
  transpose_cast_kernel<<<dim3(FF / 32, C / 32, 1), tb, 0, stream>>>(W1, w1t, C, FF);
  transpose_cast_kernel<<<dim3(C / 32, FF / 32, 1), tb, 0, stream>>>(W2, w2t, FF, C);
  ln_kernel<<<M, 256, 0, stream>>>(x, g1, be1, hbuf);
  gemm_bt_kernel<3072, 1024, 2><<<dim3(3072 / 128, M / 128), 256, 0, stream>>>(
      hbuf, qkvt, nullptr, nullptr, big);
  transpose_v_kernel<<<dim3(2, T / 32, B * H), tb, 0, stream>>>(big, vtb);
  attn_kernel<<<dim3(32, 128), 256, 0, stream>>>(big, vtb, aout);
  gemm_bt_kernel<1024, 1024, 4 | 8><<<dim3(1024 / 128, M / 128), 256, 0, stream>>>(
      aout, wot, bo, x, x2);
  ln_kernel<<<M, 256, 0, stream>>>(x2, g2, be2, hbuf);
  gemm_bt_kernel<4096, 1024, 1 | 2 | 4><<<dim3(4096 / 128, M / 128), 256, 0, stream>>>(
      hbuf, w1t, b1, nullptr, big);
  gemm_bt_kernel<1024, 4096, 4 | 8><<<dim3(1024 / 128, M / 128), 256, 0, stream>>>(
      big, w2t, b2, x2, out);
}

// Round 6
// 408.751 us; speedup vs baseline: 1.0997x; 1.0997x over previous
//
#include <hip/hip_runtime.h>
#include <stdint.h>

typedef unsigned short ushort_t;
typedef __attribute__((ext_vector_type(8))) short bf16x8;   // 8 bf16 in 4 VGPRs
typedef __attribute__((ext_vector_type(4))) float f32x4;

// ---------- helpers ----------
__device__ __forceinline__ unsigned short f2b(float f) {
  unsigned u = __float_as_uint(f);
  u += 0x7fffu + ((u >> 16) & 1u);   // round-to-nearest-even
  return (unsigned short)(u >> 16);
}

__device__ __forceinline__ void async16(const void* g, void* l) {
  __builtin_amdgcn_global_load_lds(
      (const __attribute__((address_space(1))) void*)g,
      (__attribute__((address_space(3))) void*)l, 16, 0, 0);
}

// ---------- LayerNorm (fp32 in -> bf16 out), one block per row, C=1024 ----------
__global__ __launch_bounds__(256) void ln_kernel(
    const float* __restrict__ x, const float* __restrict__ g,
    const float* __restrict__ be, ushort_t* __restrict__ out) {
  const int C = 1024;
  int row = blockIdx.x;
  const float4* xr = (const float4*)(x + (size_t)row * C);
  int tid = threadIdx.x;
  float4 v = xr[tid];
  float s = v.x + v.y + v.z + v.w;
  float sq = v.x * v.x + v.y * v.y + v.z * v.z + v.w * v.w;
  #pragma unroll
  for (int off = 32; off > 0; off >>= 1) {
    s += __shfl_xor(s, off);
    sq += __shfl_xor(sq, off);
  }
  __shared__ float ss[4], ssq[4];
  int wv = tid >> 6;
  if ((tid & 63) == 0) { ss[wv] = s; ssq[wv] = sq; }
  __syncthreads();
  s = ss[0] + ss[1] + ss[2] + ss[3];
  sq = ssq[0] + ssq[1] + ssq[2] + ssq[3];
  float mu = s * (1.f / C);
  float var = sq * (1.f / C) - mu * mu;
  float rs = rsqrtf(var + 1e-5f);
  float4 gv = ((const float4*)g)[tid];
  float4 bv = ((const float4*)be)[tid];
  ushort4 o;
  o.x = f2b((v.x - mu) * rs * gv.x + bv.x);
  o.y = f2b((v.y - mu) * rs * gv.y + bv.y);
  o.z = f2b((v.z - mu) * rs * gv.z + bv.z);
  o.w = f2b((v.w - mu) * rs * gv.w + bv.w);
  ((ushort4*)(out + (size_t)row * C))[tid] = o;
}

// ---------- batched transpose + fp32->bf16 cast: in (bz,R,Cin) -> out (bz,Cin,R) ----------
__global__ __launch_bounds__(256) void transpose_cast_kernel(
    const float* __restrict__ in, ushort_t* __restrict__ out, int R, int Cin) {
  __shared__ float tile[32][33];
  int bz = blockIdx.z;
  in += (size_t)bz * R * Cin;
  out += (size_t)bz * R * Cin;
  int c0 = blockIdx.x * 32, r0 = blockIdx.y * 32;
  int tx = threadIdx.x, ty = threadIdx.y;
  #pragma unroll
  for (int i = 0; i < 4; i++)
    tile[ty + 8 * i][tx] = in[(size_t)(r0 + ty + 8 * i) * Cin + c0 + tx];
  __syncthreads();
  #pragma unroll
  for (int i = 0; i < 4; i++)
    out[(size_t)(c0 + ty + 8 * i) * R + r0 + tx] = f2b(tile[tx][ty + 8 * i]);
}

// ---------- V transpose: QKV (4096,3072) bf16 -> Vt (B*H, 64, 2048) bf16 ----------
__global__ __launch_bounds__(256) void transpose_v_kernel(
    const ushort_t* __restrict__ qkv, ushort_t* __restrict__ vt) {
  __shared__ ushort_t tile[32][33];
  int bh = blockIdx.z;
  int b = bh >> 4, h = bh & 15;
  int d0 = blockIdx.x * 32, t0 = blockIdx.y * 32;
  int tx = threadIdx.x, ty = threadIdx.y;
  #pragma unroll
  for (int i = 0; i < 4; i++)
    tile[ty + 8 * i][tx] =
        qkv[(size_t)(b * 2048 + t0 + ty + 8 * i) * 3072 + 2048 + h * 64 + d0 + tx];
  __syncthreads();
  #pragma unroll
  for (int i = 0; i < 4; i++)
    vt[(size_t)(bh * 64 + d0 + ty + 8 * i) * 2048 + t0 + tx] = tile[tx][ty + 8 * i];
}

// ---------- GEMM: out(M,N) = A(M,K) @ Bt(N,K)^T, bf16 in ----------
// FLAGS: 1 = relu, 2 = bf16 output (else fp32), 4 = add bias, 8 = add resid.
template <int N, int K, int FLAGS>
__global__ __launch_bounds__(256, 2) void gemm_bt_kernel(
    const ushort_t* __restrict__ A, const ushort_t* __restrict__ Bt,
    const float* __restrict__ bias, const float* __restrict__ resid,
    void* __restrict__ outv) {
  __shared__ ushort_t Als[128 * 32];
  __shared__ ushort_t Bls[128 * 32];
  int tid = threadIdx.x, w = tid >> 6, lane = tid & 63, quad = lane >> 4, l16 = lane & 15;
  int bn0 = blockIdx.x * 128, bm0 = blockIdx.y * 128;
  int wm = (w >> 1) * 64, wn = (w & 1) * 64;
  f32x4 acc[4][4];
  #pragma unroll
  for (int i = 0; i < 4; i++)
    #pragma unroll
    for (int j = 0; j < 4; j++) acc[i][j] = f32x4{0.f, 0.f, 0.f, 0.f};
  const ushort_t* Ag = A + (size_t)bm0 * K;
  const ushort_t* Bg = Bt + (size_t)bn0 * K;
  int c0 = w * 128 + lane;
  int r0s = c0 >> 2, co0 = (c0 & 3) * 8;
  int c1 = c0 + 64;
  int r1s = c1 >> 2, co1 = (c1 & 3) * 8;
  for (int k0 = 0; k0 < K; k0 += 32) {
    async16(Ag + (size_t)r0s * K + k0 + co0, &Als[w * 1024]);
    async16(Bg + (size_t)r0s * K + k0 + co0, &Bls[w * 1024]);
    async16(Ag + (size_t)r1s * K + k0 + co1, &Als[w * 1024 + 512]);
    async16(Bg + (size_t)r1s * K + k0 + co1, &Bls[w * 1024 + 512]);
    __syncthreads();
    bf16x8 af[4], bf[4];
    #pragma unroll
    for (int i = 0; i < 4; i++)
      af[i] = *(const bf16x8*)&Als[(wm + i * 16 + l16) * 32 + quad * 8];
    #pragma unroll
    for (int j = 0; j < 4; j++)
      bf[j] = *(const bf16x8*)&Bls[(wn + j * 16 + l16) * 32 + quad * 8];
    #pragma unroll
    for (int i = 0; i < 4; i++)
      #pragma unroll
      for (int j = 0; j < 4; j++)
        acc[i][j] = __builtin_amdgcn_mfma_f32_16x16x32_bf16(af[i], bf[j], acc[i][j], 0, 0, 0);
    __syncthreads();
  }
  #pragma unroll
  for (int i = 0; i < 4; i++)
    #pragma unroll
    for (int j = 0; j < 4; j++)
      #pragma unroll
      for (int r = 0; r < 4; r++) {
        int row = bm0 + wm + i * 16 + quad * 4 + r;
        int col = bn0 + wn + j * 16 + l16;
        float v = acc[i][j][r];
        if constexpr (FLAGS & 4) v += bias[col];
        if constexpr (FLAGS & 8) v += resid[(size_t)row * N + col];
        if constexpr (FLAGS & 1) v = fmaxf(v, 0.f);
        if constexpr ((FLAGS & 2) != 0)
          ((ushort_t*)outv)[(size_t)row * N + col] = f2b(v);
        else
          ((float*)outv)[(size_t)row * N + col] = v;
      }
}

// ---------- causal flash attention: cooperative LDS staging + S^T softmax ----------
// 512 blocks = 32 (b,h) x 16 q-blocks of 128 rows. 4 waves; wave w owns q-subtiles
// {w, w+4} (16 rows each). Per 64-key chunk: all 256 threads stage K (64x64) and
// V^T (64x64) into LDS via coalesced global_load_lds (gemm-proven slab layout),
// then each wave reads MFMA fragments via ds_read_b128. Softmax is R5's verified
// in-lane S^T form (lane = q-row); P B-frags built via shuffles. No cross-wave
// merge needed (each wave owns complete q-rows).
__global__ __launch_bounds__(256) void attn_kernel(
    const ushort_t* __restrict__ qkv, const ushort_t* __restrict__ vt,
    ushort_t* __restrict__ out) {
  const int T = 2048, CC = 3072;
  __shared__ ushort_t Kls[2 * 64 * 32];   // slab ks: keys 0..63 x d (ks*32..+32)
  __shared__ ushort_t Vls[2 * 64 * 32];   // slab g:  d 0..63    x keys (g*32..+32)
  int fid = blockIdx.x;                    // 512
  int xslot = fid & 7, inner = fid >> 3;   // XCD swizzle
  int bh = xslot * 4 + (inner & 3);
  int qb = 15 - (inner >> 2);              // longest q-blocks first
  int b = bh >> 4, h = bh & 15;
  int q0 = qb * 128;
  int tid = threadIdx.x, w = tid >> 6, lane = tid & 63, quad = lane >> 4, l16 = lane & 15;
  // staging coords: chunk-of-8-elems c = i*256 + w*64 + lane; i = slab
  int cc = w * 64 + lane;
  int srow = cc >> 2;                      // key row (K) / d row (V)
  int sco = (lane & 3) * 8;                // element offset within 32-elem slab row
  const ushort_t* kg = qkv + (size_t)(b * T + srow) * CC + 1024 + h * 64 + sco;
  const ushort_t* vg = vt + (size_t)(bh * 64 + srow) * T + sco;
  ushort_t* kl = &Kls[(size_t)w * 512];    // wave-uniform base; +lane*16B implicit
  ushort_t* vl = &Vls[(size_t)w * 512];
  // Q fragments for subtiles w and w+4 (B-operand: n=l16 -> q-row, k=quad*8+j -> d)
  bf16x8 aq[2][2];
  f32x4 O[2][4];
  float mrun[2] = {-1e30f, -1e30f}, lrun[2] = {0.f, 0.f};
  int q0s[2], trow[2];
  #pragma unroll
  for (int si = 0; si < 2; si++) {
    int s = w + si * 4;
    q0s[si] = q0 + s * 16;
    trow[si] = q0s[si] + l16;
    const ushort_t* qp = qkv + (size_t)(b * T + q0s[si] + l16) * CC + h * 64 + quad * 8;
    aq[si][0] = *(const bf16x8*)qp;
    aq[si][1] = *(const bf16x8*)(qp + 32);
    #pragma unroll
    for (int i = 0; i < 4; i++) O[si][i] = f32x4{0.f, 0.f, 0.f, 0.f};
  }
  int src0 = (quad & 1) * 32 + l16;   // shuffle source lanes for P^T B-frag
  int src1 = src0 + 16;
  bool hiq = quad >= 2;
  int kbmax = (q0 + 127) >> 6;        // = 2*qb + 1
  for (int kb = 0; kb <= kbmax; kb++) {
    int s0 = kb * 64;
    // ---- cooperative staging (coalesced 64B segments) ----
    async16(kg + (size_t)s0 * CC, kl);
    async16(kg + (size_t)s0 * CC + 32, kl + 2048);
    async16(vg + s0, vl);
    async16(vg + s0 + 32, vl + 2048);
    __syncthreads();
    // ---- fragments from LDS (gemm-proven pattern) ----
    bf16x8 kfr[4][2], vfr[4][2];
    #pragma unroll
    for (int t = 0; t < 4; t++)
      #pragma unroll
      for (int ks = 0; ks < 2; ks++) {
        kfr[t][ks] = *(const bf16x8*)&Kls[(ks * 64 + t * 16 + l16) * 32 + quad * 8];
        vfr[t][ks] = *(const bf16x8*)&Vls[(ks * 64 + t * 16 + l16) * 32 + quad * 8];
      }
    #pragma unroll
    for (int si = 0; si < 2; si++) {
      if (s0 > q0s[si]) continue;   // fully masked for this subtile
      // S^T = K Q^T : st[t][r] = S[key=s0+t*16+quad*4+r][q=trow]
      f32x4 st[4];
      #pragma unroll
      for (int t = 0; t < 4; t++) {
        st[t] = f32x4{0.f, 0.f, 0.f, 0.f};
        #pragma unroll
        for (int ks = 0; ks < 2; ks++)
          st[t] = __builtin_amdgcn_mfma_f32_16x16x32_bf16(kfr[t][ks], aq[si][ks], st[t], 0, 0, 0);
      }
      bool diag = (kb == (q0s[si] >> 6));
      float sv[4][4];
      float vmax = -1e30f;
      #pragma unroll
      for (int t = 0; t < 4; t++)
        #pragma unroll
        for (int r = 0; r < 4; r++) {
          float sc = st[t][r] * 0.03125f;   // * C^-0.5 (faithful: 1/32)
          int scol = s0 + t * 16 + quad * 4 + r;
          if (diag && scol > trow[si]) sc = -1e30f;
          sv[t][r] = sc;
          vmax = fmaxf(vmax, sc);
        }
      vmax = fmaxf(vmax, __shfl_xor(vmax, 16));
      vmax = fmaxf(vmax, __shfl_xor(vmax, 32));
      float mnew = fmaxf(mrun[si], vmax);
      float alpha = __expf(mrun[si] - mnew);
      mrun[si] = mnew;
      float psum = 0.f;
      int pk[4][2];
      #pragma unroll
      for (int t = 0; t < 4; t++) {
        float p0 = __expf(sv[t][0] - mnew);
        float p1 = __expf(sv[t][1] - mnew);
        float p2 = __expf(sv[t][2] - mnew);
        float p3 = __expf(sv[t][3] - mnew);
        psum += (p0 + p1) + (p2 + p3);
        pk[t][0] = (int)((unsigned)f2b(p0) | ((unsigned)f2b(p1) << 16));
        pk[t][1] = (int)((unsigned)f2b(p2) | ((unsigned)f2b(p3) << 16));
      }
      psum += __shfl_xor(psum, 16);
      psum += __shfl_xor(psum, 32);
      lrun[si] = lrun[si] * alpha + psum;
      #pragma unroll
      for (int dt = 0; dt < 4; dt++) O[si][dt] *= alpha;
      // O^T += V^T P^T ; P^T B-frag via shuffles (R5-verified construction)
      #pragma unroll
      for (int g32 = 0; g32 < 2; g32++) {
        int t0 = 2 * g32, t1 = t0 + 1;
        int a0 = __shfl(pk[t0][0], src0), b0 = __shfl(pk[t1][0], src0);
        int a1 = __shfl(pk[t0][1], src0), b1 = __shfl(pk[t1][1], src0);
        int a2 = __shfl(pk[t0][0], src1), b2 = __shfl(pk[t1][0], src1);
        int a3 = __shfl(pk[t0][1], src1), b3 = __shfl(pk[t1][1], src1);
        union { int4 i; bf16x8 h; } u;
        u.i.x = hiq ? b0 : a0;
        u.i.y = hiq ? b1 : a1;
        u.i.z = hiq ? b2 : a2;
        u.i.w = hiq ? b3 : a3;
        #pragma unroll
        for (int dt = 0; dt < 4; dt++)
          O[si][dt] = __builtin_amdgcn_mfma_f32_16x16x32_bf16(vfr[dt][g32], u.h, O[si][dt], 0, 0, 0);
      }
    }
    __syncthreads();   // all LDS reads done before next chunk's staging
  }
  // ---- epilogue: direct store (each wave owns its q-rows completely) ----
  #pragma unroll
  for (int si = 0; si < 2; si++) {
    float inv = 1.f / lrun[si];
    #pragma unroll
    for (int dt = 0; dt < 4; dt++) {
      ushort4 o;
      unsigned short* op = (unsigned short*)&o;
      #pragma unroll
      for (int r = 0; r < 4; r++) op[r] = f2b(O[si][dt][r] * inv);
      *(ushort4*)&out[(size_t)(b * T + trow[si]) * 1024 + h * 64 + dt * 16 + quad * 4] = o;
    }
  }
}

// ---------- host ----------
extern "C" void kernel_launch(void* const* d_in, const int* in_sizes, int n_in,
                              void* d_out, int out_size, void* d_ws, size_t ws_size,
                              hipStream_t stream) {
  const int B = 2, T = 2048, C = 1024, H = 16, D = 64, FF = 4096;
  const int M = B * T;  // 4096
  const float* x   = (const float*)d_in[0];
  const float* Wq  = (const float*)d_in[1];
  const float* Wk  = (const float*)d_in[2];
  const float* Wv  = (const float*)d_in[3];
  const float* Wo  = (const float*)d_in[4];
  const float* bo  = (const float*)d_in[5];
  const float* W1  = (const float*)d_in[6];
  const float* b1  = (const float*)d_in[7];
  const float* W2  = (const float*)d_in[8];
  const float* b2  = (const float*)d_in[9];
  const float* g1  = (const float*)d_in[10];
  const float* be1 = (const float*)d_in[11];
  const float* g2  = (const float*)d_in[12];
  const float* be2 = (const float*)d_in[13];
  float* out = (float*)d_out;

  char* ws = (char*)d_ws;
  size_t off = 0;
  auto alloc = [&](size_t bytes) {
    void* p = ws + off;
    off += (bytes + 255) & ~(size_t)255;
    return p;
  };
  ushort_t* qkvt = (ushort_t*)alloc((size_t)3 * C * C * 2);
  ushort_t* wot  = (ushort_t*)alloc((size_t)C * C * 2);
  ushort_t* w1t  = (ushort_t*)alloc((size_t)FF * C * 2);
  ushort_t* w2t  = (ushort_t*)alloc((size_t)C * FF * 2);
  ushort_t* hbuf = (ushort_t*)alloc((size_t)M * C * 2);
  ushort_t* big  = (ushort_t*)alloc((size_t)M * FF * 2);
  ushort_t* vtb  = (ushort_t*)alloc((size_t)M * C * 2);
  ushort_t* aout = (ushort_t*)alloc((size_t)M * C * 2);
  float*    x2   = (float*)alloc((size_t)M * C * 4);

  dim3 tb(32, 8);
  transpose_cast_kernel<<<dim3(D / 32, C / 32, H), tb, 0, stream>>>(Wq, qkvt, C, D);
  transpose_cast_kernel<<<dim3(D / 32, C / 32, H), tb, 0, stream>>>(Wk, qkvt + (size_t)C * C, C, D);
  transpose_cast_kernel<<<dim3(D / 32, C / 32, H), tb, 0, stream>>>(Wv, qkvt + (size_t)2 * C * C, C, D);
  transpose_cast_kernel<<<dim3(C / 32, C / 32, 1), tb, 0, stream>>>(Wo, wot, C, C);
  transpose_cast_kernel<<<dim3(FF / 32, C / 32, 1), tb, 0, stream>>>(W1, w1t, C, FF);
  transpose_cast_kernel<<<dim3(C / 32, FF / 32, 1), tb, 0, stream>>>(W2, w2t, FF, C);
  ln_kernel<<<M, 256, 0, stream>>>(x, g1, be1, hbuf);
  gemm_bt_kernel<3072, 1024, 2><<<dim3(3072 / 128, M / 128), 256, 0, stream>>>(
      hbuf, qkvt, nullptr, nullptr, big);
  transpose_v_kernel<<<dim3(2, T / 32, B * H), tb, 0, stream>>>(big, vtb);
  attn_kernel<<<512, 256, 0, stream>>>(big, vtb, aout);
  gemm_bt_kernel<1024, 1024, 4 | 8><<<dim3(1024 / 128, M / 128), 256, 0, stream>>>(
      aout, wot, bo, x, x2);
  ln_kernel<<<M, 256, 0, stream>>>(x2, g2, be2, hbuf);
  gemm_bt_kernel<4096, 1024, 1 | 2 | 4><<<dim3(4096 / 128, M / 128), 256, 0, stream>>>(
      hbuf, w1t, b1, nullptr, big);
  gemm_bt_kernel<1024, 4096, 4 | 8><<<dim3(1024 / 128, M / 128), 256, 0, stream>>>(
      big, w2t, b2, x2, out);
}

// Round 7
// 373.362 us; speedup vs baseline: 1.2039x; 1.0948x over previous
//
#include <hip/hip_runtime.h>
#include <stdint.h>

typedef unsigned short ushort_t;
typedef __attribute__((ext_vector_type(8))) short bf16x8;   // 8 bf16 in 4 VGPRs
typedef __attribute__((ext_vector_type(4))) float f32x4;

// ---------- helpers ----------
__device__ __forceinline__ unsigned short f2b(float f) {
  unsigned u = __float_as_uint(f);
  u += 0x7fffu + ((u >> 16) & 1u);   // round-to-nearest-even
  return (unsigned short)(u >> 16);
}

__device__ __forceinline__ void async16(const void* g, void* l) {
  __builtin_amdgcn_global_load_lds(
      (const __attribute__((address_space(1))) void*)g,
      (__attribute__((address_space(3))) void*)l, 16, 0, 0);
}

// ---------- LayerNorm (fp32 in -> bf16 out), one block per row, C=1024 ----------
__global__ __launch_bounds__(256) void ln_kernel(
    const float* __restrict__ x, const float* __restrict__ g,
    const float* __restrict__ be, ushort_t* __restrict__ out) {
  const int C = 1024;
  int row = blockIdx.x;
  const float4* xr = (const float4*)(x + (size_t)row * C);
  int tid = threadIdx.x;
  float4 v = xr[tid];
  float s = v.x + v.y + v.z + v.w;
  float sq = v.x * v.x + v.y * v.y + v.z * v.z + v.w * v.w;
  #pragma unroll
  for (int off = 32; off > 0; off >>= 1) {
    s += __shfl_xor(s, off);
    sq += __shfl_xor(sq, off);
  }
  __shared__ float ss[4], ssq[4];
  int wv = tid >> 6;
  if ((tid & 63) == 0) { ss[wv] = s; ssq[wv] = sq; }
  __syncthreads();
  s = ss[0] + ss[1] + ss[2] + ss[3];
  sq = ssq[0] + ssq[1] + ssq[2] + ssq[3];
  float mu = s * (1.f / C);
  float var = sq * (1.f / C) - mu * mu;
  float rs = rsqrtf(var + 1e-5f);
  float4 gv = ((const float4*)g)[tid];
  float4 bv = ((const float4*)be)[tid];
  ushort4 o;
  o.x = f2b((v.x - mu) * rs * gv.x + bv.x);
  o.y = f2b((v.y - mu) * rs * gv.y + bv.y);
  o.z = f2b((v.z - mu) * rs * gv.z + bv.z);
  o.w = f2b((v.w - mu) * rs * gv.w + bv.w);
  ((ushort4*)(out + (size_t)row * C))[tid] = o;
}

// ---------- batched transpose + fp32->bf16 cast: in (bz,R,Cin) -> out (bz,Cin,R) ----------
__global__ __launch_bounds__(256) void transpose_cast_kernel(
    const float* __restrict__ in, ushort_t* __restrict__ out, int R, int Cin) {
  __shared__ float tile[32][33];
  int bz = blockIdx.z;
  in += (size_t)bz * R * Cin;
  out += (size_t)bz * R * Cin;
  int c0 = blockIdx.x * 32, r0 = blockIdx.y * 32;
  int tx = threadIdx.x, ty = threadIdx.y;
  #pragma unroll
  for (int i = 0; i < 4; i++)
    tile[ty + 8 * i][tx] = in[(size_t)(r0 + ty + 8 * i) * Cin + c0 + tx];
  __syncthreads();
  #pragma unroll
  for (int i = 0; i < 4; i++)
    out[(size_t)(c0 + ty + 8 * i) * R + r0 + tx] = f2b(tile[tx][ty + 8 * i]);
}

// ---------- V transpose: QKV (4096,3072) bf16 -> Vt (B*H, 64, 2048) bf16 ----------
__global__ __launch_bounds__(256) void transpose_v_kernel(
    const ushort_t* __restrict__ qkv, ushort_t* __restrict__ vt) {
  __shared__ ushort_t tile[32][33];
  int bh = blockIdx.z;
  int b = bh >> 4, h = bh & 15;
  int d0 = blockIdx.x * 32, t0 = blockIdx.y * 32;
  int tx = threadIdx.x, ty = threadIdx.y;
  #pragma unroll
  for (int i = 0; i < 4; i++)
    tile[ty + 8 * i][tx] =
        qkv[(size_t)(b * 2048 + t0 + ty + 8 * i) * 3072 + 2048 + h * 64 + d0 + tx];
  __syncthreads();
  #pragma unroll
  for (int i = 0; i < 4; i++)
    vt[(size_t)(bh * 64 + d0 + ty + 8 * i) * 2048 + t0 + tx] = tile[tx][ty + 8 * i];
}

// ---------- GEMM: out(M,N) = A(M,K) @ Bt(N,K)^T, bf16 in ----------
// FLAGS: 1 = relu, 2 = bf16 output (else fp32), 4 = add bias, 8 = add resid.
template <int N, int K, int FLAGS>
__global__ __launch_bounds__(256, 2) void gemm_bt_kernel(
    const ushort_t* __restrict__ A, const ushort_t* __restrict__ Bt,
    const float* __restrict__ bias, const float* __restrict__ resid,
    void* __restrict__ outv) {
  __shared__ ushort_t Als[128 * 32];
  __shared__ ushort_t Bls[128 * 32];
  int tid = threadIdx.x, w = tid >> 6, lane = tid & 63, quad = lane >> 4, l16 = lane & 15;
  int bn0 = blockIdx.x * 128, bm0 = blockIdx.y * 128;
  int wm = (w >> 1) * 64, wn = (w & 1) * 64;
  f32x4 acc[4][4];
  #pragma unroll
  for (int i = 0; i < 4; i++)
    #pragma unroll
    for (int j = 0; j < 4; j++) acc[i][j] = f32x4{0.f, 0.f, 0.f, 0.f};
  const ushort_t* Ag = A + (size_t)bm0 * K;
  const ushort_t* Bg = Bt + (size_t)bn0 * K;
  int c0 = w * 128 + lane;
  int r0s = c0 >> 2, co0 = (c0 & 3) * 8;
  int c1 = c0 + 64;
  int r1s = c1 >> 2, co1 = (c1 & 3) * 8;
  for (int k0 = 0; k0 < K; k0 += 32) {
    async16(Ag + (size_t)r0s * K + k0 + co0, &Als[w * 1024]);
    async16(Bg + (size_t)r0s * K + k0 + co0, &Bls[w * 1024]);
    async16(Ag + (size_t)r1s * K + k0 + co1, &Als[w * 1024 + 512]);
    async16(Bg + (size_t)r1s * K + k0 + co1, &Bls[w * 1024 + 512]);
    __syncthreads();
    bf16x8 af[4], bf[4];
    #pragma unroll
    for (int i = 0; i < 4; i++)
      af[i] = *(const bf16x8*)&Als[(wm + i * 16 + l16) * 32 + quad * 8];
    #pragma unroll
    for (int j = 0; j < 4; j++)
      bf[j] = *(const bf16x8*)&Bls[(wn + j * 16 + l16) * 32 + quad * 8];
    #pragma unroll
    for (int i = 0; i < 4; i++)
      #pragma unroll
      for (int j = 0; j < 4; j++)
        acc[i][j] = __builtin_amdgcn_mfma_f32_16x16x32_bf16(af[i], bf[j], acc[i][j], 0, 0, 0);
    __syncthreads();
  }
  #pragma unroll
  for (int i = 0; i < 4; i++)
    #pragma unroll
    for (int j = 0; j < 4; j++)
      #pragma unroll
      for (int r = 0; r < 4; r++) {
        int row = bm0 + wm + i * 16 + quad * 4 + r;
        int col = bn0 + wn + j * 16 + l16;
        float v = acc[i][j][r];
        if constexpr (FLAGS & 4) v += bias[col];
        if constexpr (FLAGS & 8) v += resid[(size_t)row * N + col];
        if constexpr (FLAGS & 1) v = fmaxf(v, 0.f);
        if constexpr ((FLAGS & 2) != 0)
          ((ushort_t*)outv)[(size_t)row * N + col] = f2b(v);
        else
          ((float*)outv)[(size_t)row * N + col] = v;
      }
}

// ---------- causal flash attention: dbuf LDS staging + S^T softmax ----------
// 1024 blocks = 32 (b,h) x 32 q-blocks of 64 rows -> 4 blocks/CU, 16 waves/CU.
// Wave w owns the single 16-row q-subtile w. Double-buffered cooperative
// staging of each 64-key K/V^T chunk: ONE barrier per chunk; chunk k+1's
// global_load_lds flies during chunk k's compute. Softmax in exp2 domain,
// lane = q-row (S^T form); P B-frags via the R5-verified shuffle build.
__global__ __launch_bounds__(256, 4) void attn_kernel(
    const ushort_t* __restrict__ qkv, const ushort_t* __restrict__ vt,
    ushort_t* __restrict__ out) {
  const int T = 2048, CC = 3072;
  __shared__ ushort_t Kls[2][2 * 64 * 32];   // [buf][slab ks][key][d-slab 32]
  __shared__ ushort_t Vls[2][2 * 64 * 32];   // [buf][slab g][d][key-slab 32]
  int fid = blockIdx.x;                       // 1024
  int bh = (fid & 7) * 4 + ((fid >> 3) & 3);  // XCD swizzle: 4 heads per XCD
  int qb = 31 - (fid >> 5);                   // longest q-blocks first
  int b = bh >> 4, h = bh & 15;
  int q0 = qb * 64;
  int tid = threadIdx.x, w = tid >> 6, lane = tid & 63, quad = lane >> 4, l16 = lane & 15;
  // staging coords: wave w covers rows w*16..w*16+16 of the 64-row chunk
  int srow = w * 16 + (lane >> 2);
  int sco = (lane & 3) * 8;
  const ushort_t* kg = qkv + (size_t)(b * T + srow) * CC + 1024 + h * 64 + sco;
  const ushort_t* vg = vt + (size_t)(bh * 64 + srow) * T + sco;
  // Q fragment (B-operand: n=l16 -> q-row, k=quad*8+j -> d)
  int q0s = q0 + w * 16;
  int trow = q0s + l16;
  const ushort_t* qp = qkv + (size_t)(b * T + trow) * CC + h * 64 + quad * 8;
  bf16x8 aq[2] = { *(const bf16x8*)qp, *(const bf16x8*)(qp + 32) };
  f32x4 O[4];
  #pragma unroll
  for (int i = 0; i < 4; i++) O[i] = f32x4{0.f, 0.f, 0.f, 0.f};
  float mrun = -1e30f, lrun = 0.f;        // log2-domain m, linear l
  const float ksc = 0.03125f * 1.44269504f;  // C^-0.5 * log2(e)
  int src0 = (quad & 1) * 32 + l16;       // shuffle sources for P^T B-frag
  int src1 = src0 + 16;
  bool hiq = quad >= 2;
  auto stage = [&](int kb, int bi) {
    int s0 = kb * 64;
    async16(kg + (size_t)s0 * CC, &Kls[bi][w * 512]);
    async16(kg + (size_t)s0 * CC + 32, &Kls[bi][2048 + w * 512]);
    async16(vg + s0, &Vls[bi][w * 512]);
    async16(vg + s0 + 32, &Vls[bi][2048 + w * 512]);
  };
  stage(0, 0);
  for (int kb = 0; kb <= qb; kb++) {
    __syncthreads();                      // staging of chunk kb landed; prior reads done
    if (kb < qb) stage(kb + 1, (kb + 1) & 1);
    int bi = kb & 1;
    int s0 = kb * 64;
    // ---- fragments from LDS ----
    bf16x8 kfr[4][2], vfr[4][2];
    #pragma unroll
    for (int t = 0; t < 4; t++)
      #pragma unroll
      for (int ks = 0; ks < 2; ks++) {
        kfr[t][ks] = *(const bf16x8*)&Kls[bi][(ks * 64 + t * 16 + l16) * 32 + quad * 8];
        vfr[t][ks] = *(const bf16x8*)&Vls[bi][(ks * 64 + t * 16 + l16) * 32 + quad * 8];
      }
    // ---- S^T = K Q^T ----
    f32x4 st[4];
    #pragma unroll
    for (int t = 0; t < 4; t++) {
      st[t] = f32x4{0.f, 0.f, 0.f, 0.f};
      #pragma unroll
      for (int ks = 0; ks < 2; ks++)
        st[t] = __builtin_amdgcn_mfma_f32_16x16x32_bf16(kfr[t][ks], aq[ks], st[t], 0, 0, 0);
    }
    // ---- softmax (exp2 domain), diag branch hoisted (block-uniform) ----
    float sv[4][4];
    float vmax = -1e30f;
    if (kb == qb) {
      #pragma unroll
      for (int t = 0; t < 4; t++)
        #pragma unroll
        for (int r = 0; r < 4; r++) {
          float sc = st[t][r] * ksc;
          int scol = s0 + t * 16 + quad * 4 + r;
          if (scol > trow) sc = -1e30f;
          sv[t][r] = sc;
          vmax = fmaxf(vmax, sc);
        }
    } else {
      #pragma unroll
      for (int t = 0; t < 4; t++)
        #pragma unroll
        for (int r = 0; r < 4; r++) {
          float sc = st[t][r] * ksc;
          sv[t][r] = sc;
          vmax = fmaxf(vmax, sc);
        }
    }
    vmax = fmaxf(vmax, __shfl_xor(vmax, 16));
    vmax = fmaxf(vmax, __shfl_xor(vmax, 32));
    float mnew = fmaxf(mrun, vmax);
    float alpha = __builtin_amdgcn_exp2f(mrun - mnew);
    mrun = mnew;
    float psum = 0.f;
    int pk[4][2];
    #pragma unroll
    for (int t = 0; t < 4; t++) {
      float p0 = __builtin_amdgcn_exp2f(sv[t][0] - mnew);
      float p1 = __builtin_amdgcn_exp2f(sv[t][1] - mnew);
      float p2 = __builtin_amdgcn_exp2f(sv[t][2] - mnew);
      float p3 = __builtin_amdgcn_exp2f(sv[t][3] - mnew);
      psum += (p0 + p1) + (p2 + p3);
      pk[t][0] = (int)((unsigned)f2b(p0) | ((unsigned)f2b(p1) << 16));
      pk[t][1] = (int)((unsigned)f2b(p2) | ((unsigned)f2b(p3) << 16));
    }
    psum += __shfl_xor(psum, 16);
    psum += __shfl_xor(psum, 32);
    lrun = lrun * alpha + psum;
    #pragma unroll
    for (int dt = 0; dt < 4; dt++) O[dt] *= alpha;
    // ---- O^T += V^T P^T (P B-frag via shuffles, R5-verified) ----
    #pragma unroll
    for (int g32 = 0; g32 < 2; g32++) {
      int t0 = 2 * g32, t1 = t0 + 1;
      int a0 = __shfl(pk[t0][0], src0), b0 = __shfl(pk[t1][0], src0);
      int a1 = __shfl(pk[t0][1], src0), b1 = __shfl(pk[t1][1], src0);
      int a2 = __shfl(pk[t0][0], src1), b2 = __shfl(pk[t1][0], src1);
      int a3 = __shfl(pk[t0][1], src1), b3 = __shfl(pk[t1][1], src1);
      union { int4 i; bf16x8 h; } u;
      u.i.x = hiq ? b0 : a0;
      u.i.y = hiq ? b1 : a1;
      u.i.z = hiq ? b2 : a2;
      u.i.w = hiq ? b3 : a3;
      #pragma unroll
      for (int dt = 0; dt < 4; dt++)
        O[dt] = __builtin_amdgcn_mfma_f32_16x16x32_bf16(vfr[dt][g32], u.h, O[dt], 0, 0, 0);
    }
  }
  // ---- epilogue ----
  float inv = 1.f / lrun;
  #pragma unroll
  for (int dt = 0; dt < 4; dt++) {
    ushort4 o;
    unsigned short* op = (unsigned short*)&o;
    #pragma unroll
    for (int r = 0; r < 4; r++) op[r] = f2b(O[dt][r] * inv);
    *(ushort4*)&out[(size_t)(b * T + trow) * 1024 + h * 64 + dt * 16 + quad * 4] = o;
  }
}

// ---------- host ----------
extern "C" void kernel_launch(void* const* d_in, const int* in_sizes, int n_in,
                              void* d_out, int out_size, void* d_ws, size_t ws_size,
                              hipStream_t stream) {
  const int B = 2, T = 2048, C = 1024, H = 16, D = 64, FF = 4096;
  const int M = B * T;  // 4096
  const float* x   = (const float*)d_in[0];
  const float* Wq  = (const float*)d_in[1];
  const float* Wk  = (const float*)d_in[2];
  const float* Wv  = (const float*)d_in[3];
  const float* Wo  = (const float*)d_in[4];
  const float* bo  = (const float*)d_in[5];
  const float* W1  = (const float*)d_in[6];
  const float* b1  = (const float*)d_in[7];
  const float* W2  = (const float*)d_in[8];
  const float* b2  = (const float*)d_in[9];
  const float* g1  = (const float*)d_in[10];
  const float* be1 = (const float*)d_in[11];
  const float* g2  = (const float*)d_in[12];
  const float* be2 = (const float*)d_in[13];
  float* out = (float*)d_out;

  char* ws = (char*)d_ws;
  size_t off = 0;
  auto alloc = [&](size_t bytes) {
    void* p = ws + off;
    off += (bytes + 255) & ~(size_t)255;
    return p;
  };
  ushort_t* qkvt = (ushort_t*)alloc((size_t)3 * C * C * 2);
  ushort_t* wot  = (ushort_t*)alloc((size_t)C * C * 2);
  ushort_t* w1t  = (ushort_t*)alloc((size_t)FF * C * 2);
  ushort_t* w2t  = (ushort_t*)alloc((size_t)C * FF * 2);
  ushort_t* hbuf = (ushort_t*)alloc((size_t)M * C * 2);
  ushort_t* big  = (ushort_t*)alloc((size_t)M * FF * 2);
  ushort_t* vtb  = (ushort_t*)alloc((size_t)M * C * 2);
  ushort_t* aout = (ushort_t*)alloc((size_t)M * C * 2);
  float*    x2   = (float*)alloc((size_t)M * C * 4);

  dim3 tb(32, 8);
  transpose_cast_kernel<<<dim3(D / 32, C / 32, H), tb, 0, stream>>>(Wq, qkvt, C, D);
  transpose_cast_kernel<<<dim3(D / 32, C / 32, H), tb, 0, stream>>>(Wk, qkvt + (size_t)C * C, C, D);
  transpose_cast_kernel<<<dim3(D / 32, C / 32, H), tb, 0, stream>>>(Wv, qkvt + (size_t)2 * C * C, C, D);
  transpose_cast_kernel<<<dim3(C / 32, C / 32, 1), tb, 0, stream>>>(Wo, wot, C, C);
  transpose_cast_kernel<<<dim3(FF / 32, C / 32, 1), tb, 0, stream>>>(W1, w1t, C, FF);
  transpose_cast_kernel<<<dim3(C / 32, FF / 32, 1), tb, 0, stream>>>(W2, w2t, FF, C);
  ln_kernel<<<M, 256, 0, stream>>>(x, g1, be1, hbuf);
  gemm_bt_kernel<3072, 1024, 2><<<dim3(3072 / 128, M / 128), 256, 0, stream>>>(
      hbuf, qkvt, nullptr, nullptr, big);
  transpose_v_kernel<<<dim3(2, T / 32, B * H), tb, 0, stream>>>(big, vtb);
  attn_kernel<<<1024, 256, 0, stream>>>(big, vtb, aout);
  gemm_bt_kernel<1024, 1024, 4 | 8><<<dim3(1024 / 128, M / 128), 256, 0, stream>>>(
      aout, wot, bo, x, x2);
  ln_kernel<<<M, 256, 0, stream>>>(x2, g2, be2, hbuf);
  gemm_bt_kernel<4096, 1024, 1 | 2 | 4><<<dim3(4096 / 128, M / 128), 256, 0, stream>>>(
      hbuf, w1t, b1, nullptr, big);
  gemm_bt_kernel<1024, 4096, 4 | 8><<<dim3(1024 / 128, M / 128), 256, 0, stream>>>(
      big, w2t, b2, x2, out);
}